// Round 5
// baseline (25.429 us; speedup 1.0000x reference)
//
#include <hip/hip_runtime.h>

#define K_TOTAL 32768
#define R_TOTAL 128
#define A_DIM   16
#define KBATCH  32     // k-points per block

// Rules-in-lanes, DPP reduction:
//   Block = 128 threads = 2 waves. Wave h owns rules [h*64, h*64+64),
//   lane l holds rule h*64+l. Folded membership constants (81 floats) live
//   in VGPRs for the whole kernel -> ZERO per-rule operand delivery.
//   Per k: x[16] is wave-uniform (scalar loads); inner loop is 5 VALU per
//   dim; (num,den) reduced across the 64 lanes with a 6-stage DPP add
//   chain (VALU pipe -- no LDS/DS traffic in the main loop at all);
//   lane j keeps k-batch element j via readlane+cndmask.
//   Final: 2 rule-halves combined through 512 B of LDS, coalesced store.

__device__ __forceinline__ float wave_sum64(float v) {
    // canonical GCN DPP reduce; result valid in lane 63
    v += __hip_ds_bpermutef(0, 0); // (never executed; placeholder removed below)
    return v;
}

__global__ __launch_bounds__(128, 2)
void fuzzy_all(const float* __restrict__ input,
               const float* __restrict__ abcd,
               const float* __restrict__ rho,
               float* __restrict__ out) {
    const int t     = threadIdx.x;
    const int lane  = t & 63;
    const int half  = t >> 6;             // which rule half this wave owns
    const int r     = half * 64 + lane;   // this lane's rule
    const int kbase = blockIdx.x * KBATCH;

    // ---- one-time: sort abcd and fold constants for this lane's rule ----
    float C0[A_DIM], C1[A_DIM], C2[A_DIM], C3[A_DIM], RH[A_DIM], BI;
    {
        const float4* ab = (const float4*)abcd + r * A_DIM;
        #pragma unroll
        for (int a = 0; a < A_DIM; ++a) {
            float4 v = ab[a];
            float v0 = v.x, v1 = v.y, v2 = v.z, v3 = v.w, s;
            s = fminf(v0, v1); v1 = fmaxf(v0, v1); v0 = s;
            s = fminf(v2, v3); v3 = fmaxf(v2, v3); v2 = s;
            s = fminf(v0, v2); v2 = fmaxf(v0, v2); v0 = s;
            s = fminf(v1, v3); v3 = fmaxf(v1, v3); v1 = s;
            s = fminf(v1, v2); v2 = fmaxf(v1, v2); v1 = s;
            float iba = __builtin_amdgcn_rcpf(v1 - v0);
            float idc = __builtin_amdgcn_rcpf(v3 - v2);
            C0[a] =  iba;
            C1[a] = -v0 * iba;
            C2[a] = -idc;
            C3[a] =  v3 * idc;
        }
        const float* rr = rho + r * (A_DIM + 1);
        #pragma unroll
        for (int a = 0; a < A_DIM; ++a) RH[a] = rr[a];
        BI = rr[A_DIM];
    }

    float resn = 0.0f, resd = 0.0f;

    #pragma unroll 2
    for (int j = 0; j < KBATCH; ++j) {
        // wave-uniform address -> scalar loads; x lives in SGPRs
        const float4* xp = (const float4*)(input + (size_t)(kbase + j) * A_DIM);
        float4 X0 = xp[0], X1 = xp[1], X2 = xp[2], X3 = xp[3];
        float sx[A_DIM] = { X0.x, X0.y, X0.z, X0.w,  X1.x, X1.y, X1.z, X1.w,
                            X2.x, X2.y, X2.z, X2.w,  X3.x, X3.y, X3.z, X3.w };

        float z = BI;
        float m[A_DIM];
        #pragma unroll
        for (int a = 0; a < A_DIM; ++a) {
            float xa   = sx[a];
            float rise = fmaf(xa, C0[a], C1[a]);
            float fall = fmaf(xa, C2[a], C3[a]);
            m[a] = fmaxf(fminf(fminf(rise, fall), 1.0f), 0.0f);  // min3 + max
            z    = fmaf(xa, RH[a], z);
        }
        // balanced product tree
        float w = ((m[0]*m[1]) * (m[2]*m[3]))   * ((m[4]*m[5])   * (m[6]*m[7]));
        w      *= ((m[8]*m[9]) * (m[10]*m[11])) * ((m[12]*m[13]) * (m[14]*m[15]));

        float nm = z * w;
        float dn = w;

        // 6-stage DPP reduce over 64 lanes (VALU pipe, no DS). lane 63 = sum.
        #define DPPADD(v, ctrl, rmask, bc) \
            v += __int_as_float(__builtin_amdgcn_update_dpp(0, __float_as_int(v), ctrl, rmask, 0xf, bc))
        DPPADD(nm, 0x111, 0xf, true);  DPPADD(dn, 0x111, 0xf, true);   // row_shr:1
        DPPADD(nm, 0x112, 0xf, true);  DPPADD(dn, 0x112, 0xf, true);   // row_shr:2
        DPPADD(nm, 0x114, 0xf, true);  DPPADD(dn, 0x114, 0xf, true);   // row_shr:4
        DPPADD(nm, 0x118, 0xf, true);  DPPADD(dn, 0x118, 0xf, true);   // row_shr:8
        DPPADD(nm, 0x142, 0xa, false); DPPADD(dn, 0x142, 0xa, false);  // row_bcast:15
        DPPADD(nm, 0x143, 0xc, false); DPPADD(dn, 0x143, 0xc, false);  // row_bcast:31
        #undef DPPADD

        float sn = __int_as_float(__builtin_amdgcn_readlane(__float_as_int(nm), 63));
        float sd = __int_as_float(__builtin_amdgcn_readlane(__float_as_int(dn), 63));
        if (lane == j) { resn = sn; resd = sd; }   // lane j keeps k = kbase+j
    }

    // combine the two rule-halves through LDS
    __shared__ float nsh[2][KBATCH];
    __shared__ float dsh[2][KBATCH];
    if (lane < KBATCH) { nsh[half][lane] = resn; dsh[half][lane] = resd; }
    __syncthreads();

    if (t < KBATCH) {
        float n = nsh[0][t] + nsh[1][t];
        float d = dsh[0][t] + dsh[1][t] + 1e-13f;
        out[kbase + t] = n * __builtin_amdgcn_rcpf(d);
    }
}

// ---------------------------------------------------------------------------
extern "C" void kernel_launch(void* const* d_in, const int* in_sizes, int n_in,
                              void* d_out, int out_size, void* d_ws, size_t ws_size,
                              hipStream_t stream) {
    const float* input = (const float*)d_in[0];   // (K, A)    fp32
    const float* abcd  = (const float*)d_in[1];   // (R, A, 4) fp32
    const float* rho   = (const float*)d_in[2];   // (R, A+1)  fp32
    float* out = (float*)d_out;                   // (K,)      fp32

    fuzzy_all<<<K_TOTAL / KBATCH, 128, 0, stream>>>(input, abcd, rho, out);
}

// Round 6
// 18.593 us; speedup vs baseline: 1.3677x; 1.3677x over previous
//
#include <hip/hip_runtime.h>

#define K_TOTAL 32768
#define R_TOTAL 128
#define A_DIM   16

#define REC_STRIDE 96     // floats per rule record (384 B, 64B-aligned groups)
// record layout (floats):
//   [ 0..15]  dims 0-3 :  A0..A3, IBA0..3, D0..3, IDC0..3   (SoA in group)
//   [16..31]  dims 4-7
//   [32..47]  dims 8-11
//   [48..63]  dims 12-15
//   [64..79]  rho[0..15]
//   [80]      bias ; [81..95] pad

// ---------------------------------------------------------------------------
// Kernel 1: fold abcd -> {A, 1/(B-A), D, 1/(D-C)} per (r,a) + copy rho.
// ---------------------------------------------------------------------------
__global__ __launch_bounds__(256) void fuzzy_pre(const float* __restrict__ abcd,
                                                 const float* __restrict__ rho,
                                                 float* __restrict__ tab) {
    int idx = blockIdx.x * 256 + threadIdx.x;
    if (idx < R_TOTAL * A_DIM) {
        int r = idx >> 4, a = idx & 15, g = a >> 2, j = a & 3;
        float4 v = ((const float4*)abcd)[idx];
        float v0 = v.x, v1 = v.y, v2 = v.z, v3 = v.w, s;
        s = fminf(v0, v1); v1 = fmaxf(v0, v1); v0 = s;
        s = fminf(v2, v3); v3 = fmaxf(v2, v3); v2 = s;
        s = fminf(v0, v2); v2 = fmaxf(v0, v2); v0 = s;
        s = fminf(v1, v3); v3 = fmaxf(v1, v3); v1 = s;
        s = fminf(v1, v2); v2 = fmaxf(v1, v2); v1 = s;
        float* rec = tab + r * REC_STRIDE + g * 16 + j;
        rec[0]  = v0;                                   // A
        rec[4]  = __builtin_amdgcn_rcpf(v1 - v0);       // 1/(B-A)
        rec[8]  = v3;                                   // D
        rec[12] = __builtin_amdgcn_rcpf(v3 - v2);       // 1/(D-C)
    } else {
        int f = idx - R_TOTAL * A_DIM;                  // rho element
        if (f < R_TOTAL * (A_DIM + 1)) {
            int r = f / (A_DIM + 1);
            int c = f - r * (A_DIM + 1);
            tab[r * REC_STRIDE + 64 + c] = rho[f];
        }
    }
}

// membership: clamp(min((x-A)*IBA, (D-x)*IDC), 0, 1) — 7 VALU, each <=1 SGPR
__device__ __forceinline__ float memb(float x, float A, float IBA, float D, float IDC) {
    float rise = (x - A) * IBA;           // v_subrev(s,v) + v_mul(s,v)
    float fall = (D - x) * IDC;           // v_sub(s,v)    + v_mul(s,v)
    return __builtin_amdgcn_fmed3f(fminf(rise, fall), 0.0f, 1.0f);
}

// ---------------------------------------------------------------------------
// Kernel 2: main. Block = 1024 threads = 16 waves; block owns 64 k-points
//   (lane = k). Wave w owns rules [w*8, w*8+8). Rule constants arrive via
//   s_load (wave-uniform index) -> zero LDS / zero per-lane load traffic.
//   Early-out: after 8 dims (p~0.34) and 12 dims (p~0.53 cumulative) the
//   whole wave's w is zero -> skip rest; z-dot runs for only ~2% of rules.
//   Skipped contributions are exact +0 => bitwise-identical accumulation.
// ---------------------------------------------------------------------------
__global__ __launch_bounds__(1024, 8)
void fuzzy_main(const float* __restrict__ input,
                const float* __restrict__ tab,
                float* __restrict__ out) {
    __shared__ float nsh[16][64];
    __shared__ float dsh[16][64];

    const int t     = threadIdx.x;
    const int lane  = t & 63;
    const int wv    = __builtin_amdgcn_readfirstlane(t >> 6);
    const int kbase = blockIdx.x * 64;

    // per-lane k-point coordinates (16 VGPRs)
    float x[A_DIM];
    {
        const float4* xp = (const float4*)(input + (size_t)(kbase + lane) * A_DIM);
        float4 a0 = xp[0], a1 = xp[1], a2 = xp[2], a3 = xp[3];
        x[0]=a0.x;  x[1]=a0.y;  x[2]=a0.z;  x[3]=a0.w;
        x[4]=a1.x;  x[5]=a1.y;  x[6]=a1.z;  x[7]=a1.w;
        x[8]=a2.x;  x[9]=a2.y;  x[10]=a2.z; x[11]=a2.w;
        x[12]=a3.x; x[13]=a3.y; x[14]=a3.z; x[15]=a3.w;
    }

    float num = 0.0f, den = 0.0f;
    const float* __restrict__ rec0 = tab + wv * 8 * REC_STRIDE;   // uniform

    for (int rr = 0; rr < 8; ++rr) {
        const float* __restrict__ rec = rec0 + rr * REC_STRIDE;   // uniform

        float w = 1.0f;
        #pragma unroll
        for (int j = 0; j < 4; ++j)
            w *= memb(x[j],     rec[j],      rec[4+j],  rec[8+j],  rec[12+j]);
        #pragma unroll
        for (int j = 0; j < 4; ++j)
            w *= memb(x[4+j],   rec[16+j],   rec[20+j], rec[24+j], rec[28+j]);

        if (__any(w != 0.0f)) {                       // wave-uniform branch
            #pragma unroll
            for (int j = 0; j < 4; ++j)
                w *= memb(x[8+j],  rec[32+j], rec[36+j], rec[40+j], rec[44+j]);
            if (__any(w != 0.0f)) {
                #pragma unroll
                for (int j = 0; j < 4; ++j)
                    w *= memb(x[12+j], rec[48+j], rec[52+j], rec[56+j], rec[60+j]);
                if (__any(w != 0.0f)) {               // ~2% of (wave,rule)
                    float z = rec[80];
                    #pragma unroll
                    for (int a = 0; a < A_DIM; ++a)
                        z = fmaf(x[a], rec[64+a], z);
                    num = fmaf(z, w, num);
                    den += w;
                }
            }
        }
    }

    nsh[wv][lane] = num;
    dsh[wv][lane] = den;
    __syncthreads();

    if (t < 64) {
        float n = 0.0f, d = 0.0f;
        #pragma unroll
        for (int c = 0; c < 16; ++c) { n += nsh[c][t]; d += dsh[c][t]; }
        out[kbase + t] = n * __builtin_amdgcn_rcpf(d + 1e-13f);
    }
}

// ---------------------------------------------------------------------------
extern "C" void kernel_launch(void* const* d_in, const int* in_sizes, int n_in,
                              void* d_out, int out_size, void* d_ws, size_t ws_size,
                              hipStream_t stream) {
    const float* input = (const float*)d_in[0];   // (K, A)    fp32
    const float* abcd  = (const float*)d_in[1];   // (R, A, 4) fp32
    const float* rho   = (const float*)d_in[2];   // (R, A+1)  fp32
    float* out = (float*)d_out;                   // (K,)      fp32
    float* tab = (float*)d_ws;                    // 128*96*4 = 48 KB

    const int pre_elems = R_TOTAL * A_DIM + R_TOTAL * (A_DIM + 1);  // 4224
    fuzzy_pre<<<(pre_elems + 255) / 256, 256, 0, stream>>>(abcd, rho, tab);
    fuzzy_main<<<K_TOTAL / 64, 1024, 0, stream>>>(input, tab, out);
}

// Round 7
// 18.026 us; speedup vs baseline: 1.4106x; 1.0314x over previous
//
#include <hip/hip_runtime.h>

#define K_TOTAL 32768
#define R_TOTAL 128
#define A_DIM   16

#define REC_STRIDE 96   // floats per rule record (384 B)
// record layout (floats):
//   [ 0..31]  stage A (dims 0-7):  IBA[8] | C1[8]=-A*IBA | NIDC[8]=-IDC | C3[8]=D*IDC
//   [32..63]  stage B (dims 8-15): same sub-layout
//   [64..79]  rho[0..15]
//   [80]      bias ; [81..95] pad

typedef float v2f __attribute__((ext_vector_type(2)));

// ---------------------------------------------------------------------------
// Kernel 1: fold abcd -> packed-pair FMA constants + copy rho.
// ---------------------------------------------------------------------------
__global__ __launch_bounds__(256) void fuzzy_pre(const float* __restrict__ abcd,
                                                 const float* __restrict__ rho,
                                                 float* __restrict__ tab) {
    int idx = blockIdx.x * 256 + threadIdx.x;
    if (idx < R_TOTAL * A_DIM) {
        int r = idx >> 4, a = idx & 15, st = a >> 3, ai = a & 7;
        float4 v = ((const float4*)abcd)[idx];
        float v0 = v.x, v1 = v.y, v2 = v.z, v3 = v.w, s;
        s = fminf(v0, v1); v1 = fmaxf(v0, v1); v0 = s;
        s = fminf(v2, v3); v3 = fmaxf(v2, v3); v2 = s;
        s = fminf(v0, v2); v2 = fmaxf(v0, v2); v0 = s;
        s = fminf(v1, v3); v3 = fmaxf(v1, v3); v1 = s;
        s = fminf(v1, v2); v2 = fmaxf(v1, v2); v1 = s;
        // v0<=v1<=v2<=v3
        float iba = __builtin_amdgcn_rcpf(v1 - v0);
        float idc = __builtin_amdgcn_rcpf(v3 - v2);
        float* base = tab + r * REC_STRIDE + st * 32;
        base[ai]      =  iba;          // IBA
        base[8 + ai]  = -v0 * iba;     // C1
        base[16 + ai] = -idc;          // NIDC
        base[24 + ai] =  v3 * idc;     // C3
    } else {
        int f = idx - R_TOTAL * A_DIM;
        if (f < R_TOTAL * (A_DIM + 1)) {
            int r = f / (A_DIM + 1);
            int c = f - r * (A_DIM + 1);
            tab[r * REC_STRIDE + 64 + c] = rho[f];  // c==16 -> bias at [80]
        }
    }
}

// membership for a dim-pair: rise=(x*IBA)+C1, fall=(x*NIDC)+C3, clamp
__device__ __forceinline__ v2f memb_pair(v2f X, const float* __restrict__ rec, int p) {
    v2f iba = *(const v2f*)(rec + 2 * p);
    v2f c1  = *(const v2f*)(rec + 8 + 2 * p);
    v2f nid = *(const v2f*)(rec + 16 + 2 * p);
    v2f c3  = *(const v2f*)(rec + 24 + 2 * p);
    v2f rise = X * iba + c1;   // pk_mul + pk_add (<=1 sgpr-pair each)
    v2f fall = X * nid + c3;
    v2f M;
    M.x = __builtin_amdgcn_fmed3f(fminf(rise.x, fall.x), 0.0f, 1.0f);
    M.y = __builtin_amdgcn_fmed3f(fminf(rise.y, fall.y), 0.0f, 1.0f);
    return M;
}

// ---------------------------------------------------------------------------
// Kernel 2: main. 512 blocks x 1024 thr (16 waves, 8/SIMD). Block owns 64
//   k's (lane = k); wave wv owns rules [wv*8, wv*8+8). Rule constants via
//   s_load (uniform) -> SGPR pairs feeding packed-fp32 VALU ops.
//   Early-out after dims 8 (skip p~.34) and 12 (p~.80); z-dot only when
//   some lane survives all 16 dims (p~.02). Skips are exact +0.
// ---------------------------------------------------------------------------
__global__ __launch_bounds__(1024, 8)
void fuzzy_main(const float* __restrict__ input,
                const float* __restrict__ tab,
                float* __restrict__ out) {
    __shared__ float nsh[16][64];
    __shared__ float dsh[16][64];

    const int t     = threadIdx.x;
    const int lane  = t & 63;
    const int wv    = __builtin_amdgcn_readfirstlane(t >> 6);
    const int kbase = blockIdx.x * 64;

    // per-lane k-point coordinates as 8 pairs
    v2f X[8];
    {
        const float4* xp = (const float4*)(input + (size_t)(kbase + lane) * A_DIM);
        float4 a0 = xp[0], a1 = xp[1], a2 = xp[2], a3 = xp[3];
        X[0] = (v2f){a0.x, a0.y}; X[1] = (v2f){a0.z, a0.w};
        X[2] = (v2f){a1.x, a1.y}; X[3] = (v2f){a1.z, a1.w};
        X[4] = (v2f){a2.x, a2.y}; X[5] = (v2f){a2.z, a2.w};
        X[6] = (v2f){a3.x, a3.y}; X[7] = (v2f){a3.z, a3.w};
    }

    float num = 0.0f, den = 0.0f;
    const float* __restrict__ rec0 = tab + wv * 8 * REC_STRIDE;   // uniform

    #pragma unroll
    for (int rr = 0; rr < 8; ++rr) {
        const float* __restrict__ rec = rec0 + rr * REC_STRIDE;   // uniform

        v2f W = (v2f){1.0f, 1.0f};
        W *= memb_pair(X[0], rec, 0);
        W *= memb_pair(X[1], rec, 1);
        W *= memb_pair(X[2], rec, 2);
        W *= memb_pair(X[3], rec, 3);
        float w8 = W.x * W.y;
        if (__any(w8 != 0.0f)) {
            const float* __restrict__ recB = rec + 32;
            W *= memb_pair(X[4], recB, 0);
            W *= memb_pair(X[5], recB, 1);
            float w12 = W.x * W.y;
            if (__any(w12 != 0.0f)) {
                W *= memb_pair(X[6], recB, 2);
                W *= memb_pair(X[7], recB, 3);
                float wf = W.x * W.y;
                if (__any(wf != 0.0f)) {
                    v2f acc = (v2f){rec[80], 0.0f};        // bias
                    #pragma unroll
                    for (int p = 0; p < 8; ++p) {
                        v2f rh = *(const v2f*)(rec + 64 + 2 * p);
                        acc += X[p] * rh;                  // pk_fma
                    }
                    float z = acc.x + acc.y;
                    num = fmaf(z, wf, num);
                    den += wf;
                }
            }
        }
    }

    nsh[wv][lane] = num;
    dsh[wv][lane] = den;
    __syncthreads();

    if (t < 64) {
        float n = 0.0f, d = 0.0f;
        #pragma unroll
        for (int c = 0; c < 16; ++c) { n += nsh[c][t]; d += dsh[c][t]; }
        out[kbase + t] = n * __builtin_amdgcn_rcpf(d + 1e-13f);
    }
}

// ---------------------------------------------------------------------------
extern "C" void kernel_launch(void* const* d_in, const int* in_sizes, int n_in,
                              void* d_out, int out_size, void* d_ws, size_t ws_size,
                              hipStream_t stream) {
    const float* input = (const float*)d_in[0];   // (K, A)    fp32
    const float* abcd  = (const float*)d_in[1];   // (R, A, 4) fp32
    const float* rho   = (const float*)d_in[2];   // (R, A+1)  fp32
    float* out = (float*)d_out;                   // (K,)      fp32
    float* tab = (float*)d_ws;                    // 128*96*4 = 48 KB

    const int pre_elems = R_TOTAL * A_DIM + R_TOTAL * (A_DIM + 1);  // 4224
    fuzzy_pre<<<(pre_elems + 255) / 256, 256, 0, stream>>>(abcd, rho, tab);
    fuzzy_main<<<K_TOTAL / 64, 1024, 0, stream>>>(input, tab, out);
}